// Round 4
// baseline (3471.586 us; speedup 1.0000x reference)
//
#include <hip/hip_runtime.h>
#include <math.h>

#define BB 2
#define CCH 64
#define NN 4096
#define KK 9
#define TT 2
#define C2 128
#define C4 256
#define R1 (BB*NN)        /* 8192  */
#define RG (BB*NN*KK)     /* 73728 */
#define SPLIT 16
#define CHUNK (NN/SPLIT)  /* 256 */

// ---- workspace layout (floats), total 5194240 floats = 20.8 MB ----
#define WS_TOTAL 5194240ull

__device__ __forceinline__ float gelu(float v){ return 0.5f*v*(1.f + erff(v*0.70710678118654752f)); }

__global__ void k_zero(float* __restrict__ o, int n){
  int i = blockIdx.x*256 + threadIdx.x;
  if (i < n) o[i] = 0.f;
}

// ---------------- transpose x (B,C,N) -> x0f (B,N,C) ----------------
__global__ void k_transpose(const float* __restrict__ x, float* __restrict__ x0f){
  int idx = blockIdx.x*256 + threadIdx.x;
  if (idx >= BB*NN*CCH) return;
  int c = idx & (CCH-1);
  int n = (idx >> 6) & (NN-1);
  int b = idx >> 18;
  x0f[idx] = x[(size_t)(b*CCH + c)*NN + n];
}

// ---------------- GEMM: Y(R,Cc) = X(R,D) @ W(D,Cc) + bias ----------------
__global__ void k_gemm(const float* __restrict__ X, const float* __restrict__ W,
                       const float* __restrict__ bias, float* __restrict__ Y,
                       int R, int D, int Cc){
  int idx = blockIdx.x*256 + threadIdx.x;
  if (idx >= R*Cc) return;
  int c = idx % Cc; int r = idx / Cc;
  const float* xr = X + (size_t)r*D;
  float acc = bias[c];
  for (int d=0; d<D; d++) acc = fmaf(xr[d], W[d*Cc + c], acc);
  Y[(size_t)idx] = acc;
}

// ---------------- per-channel sum/sumsq partials (no atomics) ----------------
__global__ void k_colstats(const float* __restrict__ Y, int R, int Cc, float* __restrict__ part){
  __shared__ float s1[256], s2[256];
  int tid = threadIdx.x;
  int tpc = 256 / Cc;
  int c = tid % Cc; int rsub = tid / Cc;
  float sm=0.f, ss=0.f;
  for (int r = blockIdx.x*tpc + rsub; r < R; r += gridDim.x*tpc){
    float v = Y[(size_t)r*Cc + c];
    sm += v; ss += v*v;
  }
  s1[tid]=sm; s2[tid]=ss;
  __syncthreads();
  if (tid < Cc){
    for (int u=1; u<tpc; u++){ sm += s1[tid + u*Cc]; ss += s2[tid + u*Cc]; }
    part[blockIdx.x*2*Cc + tid] = sm;
    part[blockIdx.x*2*Cc + Cc + tid] = ss;
  }
}

__global__ void k_finalize(const float* __restrict__ part, int G, int Cc,
                           const float* __restrict__ g, const float* __restrict__ bt,
                           float Rf, float* __restrict__ scsh){
  int c = threadIdx.x;
  if (c >= Cc) return;
  float sm=0.f, ss=0.f;
  for (int u=0; u<G; u++){ sm += part[u*2*Cc + c]; ss += part[u*2*Cc + Cc + c]; }
  float mean = sm / Rf;
  float var = fmaxf(ss / Rf - mean*mean, 0.f);
  float sc = g[c] * rsqrtf(var + 1e-5f);
  scsh[c] = sc;
  scsh[Cc + c] = bt[c] - mean*sc;
}

// ---------------- BN apply variants ----------------
__global__ void k_apply(float* __restrict__ Y, const float* __restrict__ scsh, int n){
  int idx = blockIdx.x*256+threadIdx.x;
  if (idx >= n) return;
  int c = idx & 63;
  Y[idx] = fmaf(Y[idx], scsh[c], scsh[64+c]);
}
__global__ void k_apply_res(const float* __restrict__ Y, const float* __restrict__ scsh,
                            const float* __restrict__ addv, float* __restrict__ outv, int n){
  int idx = blockIdx.x*256+threadIdx.x;
  if (idx >= n) return;
  int c = idx & 63;
  outv[idx] = fmaf(Y[idx], scsh[c], scsh[64+c]) + addv[idx];
}

// ---------------- row normalize (LDS reduction) ----------------
__global__ void k_rownorm(const float* __restrict__ h, float* __restrict__ xn,
                          float* __restrict__ sq){
  __shared__ float red[64];
  int r = blockIdx.x; int c = threadIdx.x;
  float v = h[(size_t)r*64 + c];
  red[c] = v*v;
  __syncthreads();
  for (int off=32; off; off>>=1){
    if (c < off) red[c] += red[c+off];
    __syncthreads();
  }
  float den = fmaxf(sqrtf(red[0]), 1e-12f);
  __syncthreads();
  float xv = v / den;
  xn[(size_t)r*64 + c] = xv;
  red[c] = xv*xv;
  __syncthreads();
  for (int off=32; off; off>>=1){
    if (c < off) red[c] += red[c+off];
    __syncthreads();
  }
  if (c == 0) sq[r] = red[0];
}

// ---------------- KNN: per-thread row, streaming top-9 over a j-chunk ----------------
__global__ void k_knn(const float* __restrict__ xn, const float* __restrict__ sq,
                      float* __restrict__ pd, int* __restrict__ pi_){
  int bx = blockIdx.x;
  if (bx >= 512) return;
  int b = bx >> 8;
  int rem = bx & 255;
  int split = rem >> 4;
  int rb = rem & 15;
  int i = rb*256 + threadIdx.x;
  const float* xb = xn + (size_t)b*NN*64;
  const float* sqb = sq + (size_t)b*NN;
  float4 xi[16];
  const float4* xir = (const float4*)(xb + (size_t)i*64);
  #pragma unroll
  for (int q=0;q<16;q++) xi[q] = xir[q];
  float sqi = sqb[i];
  float bd[9]; int bi[9];
  #pragma unroll
  for (int q=0;q<9;q++){ bd[q] = INFINITY; bi[q] = 0x7fffffff; }
  float wd = INFINITY; int wi = 0x7fffffff;
  int j0 = split*CHUNK;
  for (int j=j0; j<j0+CHUNK; j++){
    const float4* xjr = (const float4*)(xb + (size_t)j*64);
    float ax=0.f, ay=0.f, az=0.f, aw=0.f;
    #pragma unroll
    for (int q=0;q<16;q++){
      float4 v = xjr[q];
      ax = fmaf(xi[q].x, v.x, ax);
      ay = fmaf(xi[q].y, v.y, ay);
      az = fmaf(xi[q].z, v.z, az);
      aw = fmaf(xi[q].w, v.w, aw);
    }
    float dot = (ax+ay)+(az+aw);
    float d = sqi + sqb[j] - 2.f*dot;
    if (d < wd || (d == wd && j < wi)){
      bool done=false;
      #pragma unroll
      for (int q=0;q<9;q++){
        if (!done && bd[q]==wd && bi[q]==wi){ bd[q]=d; bi[q]=j; done=true; }
      }
      wd = bd[0]; wi = bi[0];
      #pragma unroll
      for (int q=1;q<9;q++){
        if (bd[q] > wd || (bd[q]==wd && bi[q] > wi)){ wd=bd[q]; wi=bi[q]; }
      }
    }
  }
  size_t base = (((size_t)(b*NN + i))*SPLIT + split)*9;
  #pragma unroll
  for (int q=0;q<9;q++){ pd[base+q]=bd[q]; pi_[base+q]=bi[q]; }
}

// ---------------- merge per-row candidates -> 9 lex-smallest ----------------
__global__ void k_knnmerge(const float* __restrict__ pd, const int* __restrict__ pi_,
                           int* __restrict__ idxf){
  int row = blockIdx.x*256 + threadIdx.x;
  if (row >= R1) return;
  size_t base = (size_t)row * (SPLIT*9);
  int sel[9];
  #pragma unroll
  for (int s=0;s<9;s++) sel[s] = -1;
  for (int s=0;s<9;s++){
    float bdv = INFINITY; int biv = 0x7fffffff;
    for (int q=0;q<SPLIT*9;q++){
      int ji = pi_[base+q];
      bool used=false;
      #pragma unroll
      for (int u=0;u<9;u++) used = used || (sel[u]==ji);
      if (used) continue;
      float dv = pd[base+q];
      if (dv < bdv || (dv==bdv && ji < biv)){ bdv=dv; biv=ji; }
    }
    sel[s] = biv;
    idxf[(size_t)row*9 + s] = biv & (NN-1);
  }
}

// ---------------- edge conv pass 1: column stats only ----------------
__global__ void k_edgestats(const float* __restrict__ h, const int* __restrict__ idxf,
                            const float* __restrict__ Wgf, const float* __restrict__ bg,
                            float* __restrict__ part){
  __shared__ float xiL[64];
  __shared__ float dxL[9*64];
  __shared__ int kidx[9];
  int tid = threadIdx.x;
  int c = tid;
  float bias = bg[c];
  float sm=0.f, ss=0.f;
  for (int u=0; u<16; u++){
    int node = blockIdx.x*16 + u;
    int b = node >> 12;
    __syncthreads();
    if (tid < 64) xiL[tid] = h[(size_t)node*64 + tid];
    if (tid < 9) kidx[tid] = idxf[(size_t)node*9 + tid] & (NN-1);
    __syncthreads();
    for (int r2 = tid; r2 < 9*64; r2 += 128){
      int k = r2 >> 6; int d = r2 & 63;
      dxL[r2] = h[((size_t)(b*NN + kidx[k]))*64 + d] - xiL[d];
    }
    __syncthreads();
    float common = bias;
    for (int d=0; d<64; d++) common = fmaf(xiL[d], Wgf[d*C2 + c], common);
    float acc[9];
    #pragma unroll
    for (int k=0;k<9;k++) acc[k]=0.f;
    for (int d=0; d<64; d++){
      float w = Wgf[(64+d)*C2 + c];
      #pragma unroll
      for (int k=0;k<9;k++) acc[k] = fmaf(dxL[k*64+d], w, acc[k]);
    }
    #pragma unroll
    for (int k=0;k<9;k++){ float v = common + acc[k]; sm += v; ss += v*v; }
  }
  part[blockIdx.x*256 + c] = sm;
  part[blockIdx.x*256 + 128 + c] = ss;
}

// ---------------- edge conv pass 2: recompute + BN + gelu + max over K ----------
__global__ void k_edgemax(const float* __restrict__ h, const int* __restrict__ idxf,
                          const float* __restrict__ Wgf, const float* __restrict__ bg,
                          const float* __restrict__ scsh, float* __restrict__ gmax){
  __shared__ float xiL[64];
  __shared__ float dxL[9*64];
  __shared__ int kidx[9];
  int node = blockIdx.x;
  int b = node >> 12;
  int tid = threadIdx.x;
  if (tid < 64) xiL[tid] = h[(size_t)node*64 + tid];
  if (tid < 9) kidx[tid] = idxf[(size_t)node*9 + tid] & (NN-1);
  __syncthreads();
  for (int r2 = tid; r2 < 9*64; r2 += 128){
    int k = r2 >> 6; int d = r2 & 63;
    dxL[r2] = h[((size_t)(b*NN + kidx[k]))*64 + d] - xiL[d];
  }
  __syncthreads();
  int c = tid;
  float common = bg[c];
  for (int d=0; d<64; d++) common = fmaf(xiL[d], Wgf[d*C2 + c], common);
  float acc[9];
  #pragma unroll
  for (int k=0;k<9;k++) acc[k]=0.f;
  for (int d=0; d<64; d++){
    float w = Wgf[(64+d)*C2 + c];
    #pragma unroll
    for (int k=0;k<9;k++) acc[k] = fmaf(dxL[k*64+d], w, acc[k]);
  }
  float sc = scsh[c], sh = scsh[C2 + c];
  float m = -INFINITY;
  #pragma unroll
  for (int k=0;k<9;k++){
    float v = fmaf(common + acc[k], sc, sh);
    m = fmaxf(m, gelu(v));
  }
  gmax[(size_t)node*C2 + c] = m;
}

// ---------------- FFN pass 1: fused GEMM(64->256) + column stats ----------------
__global__ void k_ffn1stats(const float* __restrict__ outt, const float* __restrict__ Wf1f,
                            const float* __restrict__ bf1v, float* __restrict__ part){
  int c = threadIdx.x;
  float bias = bf1v[c];
  float sm=0.f, ss=0.f;
  for (int u=0; u<32; u++){
    int r = blockIdx.x*32 + u;
    const float* xr = outt + (size_t)r*64;
    float acc = bias;
    for (int d=0; d<64; d++) acc = fmaf(xr[d], Wf1f[d*C4 + c], acc);
    sm += acc; ss += acc*acc;
  }
  part[blockIdx.x*512 + c] = sm;
  part[blockIdx.x*512 + 256 + c] = ss;
}

// ---------------- FFN pass 2: recompute + BN + gelu + GEMM(256->64) ----------------
__global__ void k_ffn2(const float* __restrict__ outt, const float* __restrict__ Wf1f,
                       const float* __restrict__ bf1v, const float* __restrict__ scsh,
                       const float* __restrict__ Wf2f, const float* __restrict__ bf2v,
                       float* __restrict__ Yf2){
  __shared__ float xr[64];
  __shared__ float fL[256];
  __shared__ float red[256];
  int r = blockIdx.x; int tid = threadIdx.x;
  if (tid < 64) xr[tid] = outt[(size_t)r*64 + tid];
  __syncthreads();
  float acc = bf1v[tid];
  for (int d=0; d<64; d++) acc = fmaf(xr[d], Wf1f[d*C4 + tid], acc);
  float v = fmaf(acc, scsh[tid], scsh[C4 + tid]);
  fL[tid] = gelu(v);
  __syncthreads();
  int g = tid >> 6, c = tid & 63;
  float p = 0.f;
  for (int dd=0; dd<64; dd++){
    int d = g*64 + dd;
    p = fmaf(fL[d], Wf2f[d*64 + c], p);
  }
  red[tid] = p;
  __syncthreads();
  if (tid < 64){
    float y = bf2v[tid] + red[tid] + red[64+tid] + red[128+tid] + red[192+tid];
    Yf2[(size_t)r*64 + tid] = y;
  }
}

// ---------------- alpha-mix + transpose -> output (T,B,C,N) fp32 ----------------
__global__ void k_mix(const float* __restrict__ f0, const float* __restrict__ f1,
                      const float* __restrict__ alpha, float* __restrict__ outv){
  int idx = blockIdx.x*256 + threadIdx.x;
  if (idx >= TT*BB*CCH*NN) return;
  int n = idx & (NN-1);
  int c = (idx >> 12) & 63;
  int b = (idx >> 18) & 1;
  int i = idx >> 19;
  float a0 = alpha[i*TT + 0];
  float a1 = alpha[i*TT + 1];
  size_t fi = ((size_t)(b*NN + n))*64 + c;
  outv[idx] = a0*f0[fi] + a1*f1[fi];
}

extern "C" void kernel_launch(void* const* d_in, const int* in_sizes, int n_in,
                              void* d_out, int out_size, void* d_ws, size_t ws_size,
                              hipStream_t stream){
  float* outp = (float*)d_out;

  // ---- validate assumptions; on mismatch zero the output and bail ----
  static const int expect[22] = {
    524288, 8192, 128, 128, 128, 32768, 256, 256, 256, 16384, 128, 128, 128,
    32768, 512, 512, 512, 32768, 128, 128, 128, 4
  };
  bool ok = (n_in == 22) && (out_size == TT*BB*CCH*NN) &&
            (ws_size >= WS_TOTAL*sizeof(float));
  if (ok){
    for (int i=0;i<22;i++) if (in_sizes[i] != expect[i]) { ok = false; break; }
  }
  if (!ok){
    k_zero<<<(out_size+255)/256,256,0,stream>>>(outp, out_size);
    return;
  }

  const float* x   = (const float*)d_in[0];
  const float* W1  = (const float*)d_in[1];
  const float* b1  = (const float*)d_in[2];
  const float* g1  = (const float*)d_in[3];
  const float* bt1 = (const float*)d_in[4];
  const float* Wg  = (const float*)d_in[5];
  const float* bg  = (const float*)d_in[6];
  const float* gg  = (const float*)d_in[7];
  const float* btg = (const float*)d_in[8];
  const float* W2  = (const float*)d_in[9];
  const float* b2v = (const float*)d_in[10];
  const float* g2  = (const float*)d_in[11];
  const float* bt2 = (const float*)d_in[12];
  const float* Wf1 = (const float*)d_in[13];
  const float* bf1v= (const float*)d_in[14];
  const float* gf1 = (const float*)d_in[15];
  const float* btf1= (const float*)d_in[16];
  const float* Wf2 = (const float*)d_in[17];
  const float* bf2v= (const float*)d_in[18];
  const float* gf2 = (const float*)d_in[19];
  const float* btf2= (const float*)d_in[20];
  const float* alpha=(const float*)d_in[21];
  float* ws = (float*)d_ws;

  float* x0f  = ws + 0;
  float* hbuf = ws + 524288;
  float* xnb  = ws + 1048576;
  float* sqb  = ws + 1572864;
  float* part = ws + 1581056;
  float* scsh = ws + 1712128;
  int*   idxf = (int*)(ws + 1712640);
  float* f0   = ws + 1786368;
  float* f1b  = ws + 2310656;
  float* Rbig = ws + 2834944;
  float* pdist = Rbig;
  int*   pidx  = (int*)(Rbig + (size_t)R1*SPLIT*9);
  float* gmaxb = Rbig;
  float* outt  = Rbig + 1048576;
  float* Y2    = Rbig + 1572864;
  float* Yf2   = Rbig;

  k_transpose<<<2048,256,0,stream>>>(x, x0f);
  float* feats[2] = {f0, f1b};
  for (int t=0; t<TT; t++){
    // h = BN(x0 @ W1 + b1)
    k_gemm<<<2048,256,0,stream>>>(x0f, W1 + t*CCH*CCH, b1 + t*64, hbuf, R1, 64, 64);
    k_colstats<<<64,256,0,stream>>>(hbuf, R1, 64, part);
    k_finalize<<<1,64,0,stream>>>(part, 64, 64, g1 + t*64, bt1 + t*64, (float)R1, scsh);
    k_apply<<<2048,256,0,stream>>>(hbuf, scsh, R1*64);
    // knn on normalized h
    k_rownorm<<<R1,64,0,stream>>>(hbuf, xnb, sqb);
    k_knn<<<512,256,0,stream>>>(xnb, sqb, pdist, pidx);
    k_knnmerge<<<R1/256,256,0,stream>>>(pdist, pidx, idxf);
    // edge conv (two-pass)
    k_edgestats<<<512,128,0,stream>>>(hbuf, idxf, Wg + t*C2*C2, bg + t*C2, part);
    k_finalize<<<1,128,0,stream>>>(part, 512, 128, gg + t*C2, btg + t*C2, (float)RG, scsh);
    k_edgemax<<<R1,128,0,stream>>>(hbuf, idxf, Wg + t*C2*C2, bg + t*C2, scsh, gmaxb);
    // out = BN(gmax @ W2 + b2) + x0
    k_gemm<<<2048,256,0,stream>>>(gmaxb, W2 + t*C2*CCH, b2v + t*64, Y2, R1, 128, 64);
    k_colstats<<<64,256,0,stream>>>(Y2, R1, 64, part);
    k_finalize<<<1,64,0,stream>>>(part, 64, 64, g2 + t*64, bt2 + t*64, (float)R1, scsh);
    k_apply_res<<<2048,256,0,stream>>>(Y2, scsh, x0f, outt, R1*64);
    // FFN (two-pass)
    k_ffn1stats<<<256,256,0,stream>>>(outt, Wf1 + t*CCH*C4, bf1v + t*C4, part);
    k_finalize<<<1,256,0,stream>>>(part, 256, 256, gf1 + t*C4, btf1 + t*C4, (float)R1, scsh);
    k_ffn2<<<R1,256,0,stream>>>(outt, Wf1 + t*CCH*C4, bf1v + t*C4, scsh, Wf2 + t*C4*CCH, bf2v + t*64, Yf2);
    k_colstats<<<64,256,0,stream>>>(Yf2, R1, 64, part);
    k_finalize<<<1,64,0,stream>>>(part, 64, 64, gf2 + t*64, btf2 + t*64, (float)R1, scsh);
    k_apply_res<<<2048,256,0,stream>>>(Yf2, scsh, outt, feats[t], R1*64);
  }
  k_mix<<<4096,256,0,stream>>>(f0, f1b, alpha, outp);
}

// Round 5
// 2551.719 us; speedup vs baseline: 1.3605x; 1.3605x over previous
//
#include <hip/hip_runtime.h>
#include <math.h>

#define BB 2
#define CCH 64
#define NN 4096
#define KK 9
#define TT 2
#define C2 128
#define C4 256
#define R1 (BB*NN)        /* 8192  */
#define RG (BB*NN*KK)     /* 73728 */
#define SPLIT 16
#define CHUNK (NN/SPLIT)  /* 256 */

// ---- workspace layout (floats), total 5194240 floats = 20.8 MB ----
#define WS_TOTAL 5194240ull

__device__ __forceinline__ float gelu(float v){ return 0.5f*v*(1.f + erff(v*0.70710678118654752f)); }

__global__ void k_zero(float* __restrict__ o, int n){
  int i = blockIdx.x*256 + threadIdx.x;
  if (i < n) o[i] = 0.f;
}

// ---------------- transpose x (B,C,N) -> x0f (B,N,C) ----------------
__global__ void k_transpose(const float* __restrict__ x, float* __restrict__ x0f){
  int idx = blockIdx.x*256 + threadIdx.x;
  if (idx >= BB*NN*CCH) return;
  int c = idx & (CCH-1);
  int n = (idx >> 6) & (NN-1);
  int b = idx >> 18;
  x0f[idx] = x[(size_t)(b*CCH + c)*NN + n];
}

// ---------------- GEMM: Y(R,Cc) = X(R,D) @ W(D,Cc) + bias ----------------
__global__ void k_gemm(const float* __restrict__ X, const float* __restrict__ W,
                       const float* __restrict__ bias, float* __restrict__ Y,
                       int R, int D, int Cc){
  int idx = blockIdx.x*256 + threadIdx.x;
  if (idx >= R*Cc) return;
  int c = idx % Cc; int r = idx / Cc;
  const float* xr = X + (size_t)r*D;
  float acc = bias[c];
  for (int d=0; d<D; d++) acc = fmaf(xr[d], W[d*Cc + c], acc);
  Y[(size_t)idx] = acc;
}

// ---------------- per-channel sum/sumsq partials (no atomics) ----------------
__global__ void k_colstats(const float* __restrict__ Y, int R, int Cc, float* __restrict__ part){
  __shared__ float s1[256], s2[256];
  int tid = threadIdx.x;
  int tpc = 256 / Cc;
  int c = tid % Cc; int rsub = tid / Cc;
  float sm=0.f, ss=0.f;
  for (int r = blockIdx.x*tpc + rsub; r < R; r += gridDim.x*tpc){
    float v = Y[(size_t)r*Cc + c];
    sm += v; ss += v*v;
  }
  s1[tid]=sm; s2[tid]=ss;
  __syncthreads();
  if (tid < Cc){
    for (int u=1; u<tpc; u++){ sm += s1[tid + u*Cc]; ss += s2[tid + u*Cc]; }
    part[blockIdx.x*2*Cc + tid] = sm;
    part[blockIdx.x*2*Cc + Cc + tid] = ss;
  }
}

__global__ void k_finalize(const float* __restrict__ part, int G, int Cc,
                           const float* __restrict__ g, const float* __restrict__ bt,
                           float Rf, float* __restrict__ scsh){
  int c = threadIdx.x;
  if (c >= Cc) return;
  float sm=0.f, ss=0.f;
  for (int u=0; u<G; u++){ sm += part[u*2*Cc + c]; ss += part[u*2*Cc + Cc + c]; }
  float mean = sm / Rf;
  float var = fmaxf(ss / Rf - mean*mean, 0.f);
  float sc = g[c] * rsqrtf(var + 1e-5f);
  scsh[c] = sc;
  scsh[Cc + c] = bt[c] - mean*sc;
}

// ---------------- BN apply variants ----------------
__global__ void k_apply(float* __restrict__ Y, const float* __restrict__ scsh, int n){
  int idx = blockIdx.x*256+threadIdx.x;
  if (idx >= n) return;
  int c = idx & 63;
  Y[idx] = fmaf(Y[idx], scsh[c], scsh[64+c]);
}
__global__ void k_apply_res(const float* __restrict__ Y, const float* __restrict__ scsh,
                            const float* __restrict__ addv, float* __restrict__ outv, int n){
  int idx = blockIdx.x*256+threadIdx.x;
  if (idx >= n) return;
  int c = idx & 63;
  outv[idx] = fmaf(Y[idx], scsh[c], scsh[64+c]) + addv[idx];
}

// ---------------- row normalize (LDS reduction) ----------------
__global__ void k_rownorm(const float* __restrict__ h, float* __restrict__ xn,
                          float* __restrict__ sq){
  __shared__ float red[64];
  int r = blockIdx.x; int c = threadIdx.x;
  float v = h[(size_t)r*64 + c];
  red[c] = v*v;
  __syncthreads();
  for (int off=32; off; off>>=1){
    if (c < off) red[c] += red[c+off];
    __syncthreads();
  }
  float den = fmaxf(sqrtf(red[0]), 1e-12f);
  __syncthreads();
  float xv = v / den;
  xn[(size_t)r*64 + c] = xv;
  red[c] = xv*xv;
  __syncthreads();
  for (int off=32; off; off>>=1){
    if (c < off) red[c] += red[c+off];
    __syncthreads();
  }
  if (c == 0) sq[r] = red[0];
}

// ---------------- KNN: per-thread row, streaming top-9 over a j-chunk ----------------
__global__ void k_knn(const float* __restrict__ xn, const float* __restrict__ sq,
                      float* __restrict__ pd, int* __restrict__ pi_){
  int bx = blockIdx.x;
  if (bx >= 512) return;
  int b = bx >> 8;
  int rem = bx & 255;
  int split = rem >> 4;
  int rb = rem & 15;
  int i = rb*256 + threadIdx.x;
  const float* xb = xn + (size_t)b*NN*64;
  const float* sqb = sq + (size_t)b*NN;
  float4 xi[16];
  const float4* xir = (const float4*)(xb + (size_t)i*64);
  #pragma unroll
  for (int q=0;q<16;q++) xi[q] = xir[q];
  float sqi = sqb[i];
  float bd[9]; int bi[9];
  #pragma unroll
  for (int q=0;q<9;q++){ bd[q] = INFINITY; bi[q] = 0x7fffffff; }
  float wd = INFINITY; int wi = 0x7fffffff;
  int j0 = split*CHUNK;
  for (int j=j0; j<j0+CHUNK; j++){
    const float4* xjr = (const float4*)(xb + (size_t)j*64);
    float ax=0.f, ay=0.f, az=0.f, aw=0.f;
    #pragma unroll
    for (int q=0;q<16;q++){
      float4 v = xjr[q];
      ax = fmaf(xi[q].x, v.x, ax);
      ay = fmaf(xi[q].y, v.y, ay);
      az = fmaf(xi[q].z, v.z, az);
      aw = fmaf(xi[q].w, v.w, aw);
    }
    float dot = (ax+ay)+(az+aw);
    float d = sqi + sqb[j] - 2.f*dot;
    if (d < wd || (d == wd && j < wi)){
      bool done=false;
      #pragma unroll
      for (int q=0;q<9;q++){
        if (!done && bd[q]==wd && bi[q]==wi){ bd[q]=d; bi[q]=j; done=true; }
      }
      wd = bd[0]; wi = bi[0];
      #pragma unroll
      for (int q=1;q<9;q++){
        if (bd[q] > wd || (bd[q]==wd && bi[q] > wi)){ wd=bd[q]; wi=bi[q]; }
      }
    }
  }
  size_t base = (((size_t)(b*NN + i))*SPLIT + split)*9;
  #pragma unroll
  for (int q=0;q<9;q++){ pd[base+q]=bd[q]; pi_[base+q]=bi[q]; }
}

// ---------------- merge: one WAVE per row; 144 distinct candidates -> 9 smallest ----
// (splits cover disjoint j ranges, so candidates are distinct: no dedupe needed)
__global__ void k_knnmerge(const float* __restrict__ pd, const int* __restrict__ pi_,
                           int* __restrict__ idxf){
  int lane = threadIdx.x & 63;
  int row = blockIdx.x*4 + (threadIdx.x >> 6);
  if (row >= R1) return;
  size_t base = (size_t)row * (SPLIT*9);
  float d0, d1, d2 = INFINITY;
  int   j0, j1, j2 = 0x7fffffff;
  d0 = pd[base + lane];        j0 = pi_[base + lane];
  d1 = pd[base + 64 + lane];   j1 = pi_[base + 64 + lane];
  if (lane < 16){ d2 = pd[base + 128 + lane]; j2 = pi_[base + 128 + lane]; }
  #pragma unroll
  for (int s=0; s<9; s++){
    float ld = d0; int lj = j0;
    if (d1 < ld || (d1 == ld && j1 < lj)){ ld = d1; lj = j1; }
    if (d2 < ld || (d2 == ld && j2 < lj)){ ld = d2; lj = j2; }
    #pragma unroll
    for (int off=1; off<64; off<<=1){
      float od = __shfl_xor(ld, off, 64);
      int   oj = __shfl_xor(lj, off, 64);
      if (od < ld || (od == ld && oj < lj)){ ld = od; lj = oj; }
    }
    if (lane == 0) idxf[(size_t)row*9 + s] = lj & (NN-1);
    if (j0 == lj){ d0 = INFINITY; j0 = 0x7fffffff; }
    if (j1 == lj){ d1 = INFINITY; j1 = 0x7fffffff; }
    if (j2 == lj){ d2 = INFINITY; j2 = 0x7fffffff; }
  }
}

// ---------------- edge conv pass 1: column stats only ----------------
__global__ void k_edgestats(const float* __restrict__ h, const int* __restrict__ idxf,
                            const float* __restrict__ Wgf, const float* __restrict__ bg,
                            float* __restrict__ part){
  __shared__ float xiL[64];
  __shared__ float dxL[9*64];
  __shared__ int kidx[9];
  int tid = threadIdx.x;
  int c = tid;
  float bias = bg[c];
  float sm=0.f, ss=0.f;
  for (int u=0; u<16; u++){
    int node = blockIdx.x*16 + u;
    int b = node >> 12;
    __syncthreads();
    if (tid < 64) xiL[tid] = h[(size_t)node*64 + tid];
    if (tid < 9) kidx[tid] = idxf[(size_t)node*9 + tid] & (NN-1);
    __syncthreads();
    for (int r2 = tid; r2 < 9*64; r2 += 128){
      int k = r2 >> 6; int d = r2 & 63;
      dxL[r2] = h[((size_t)(b*NN + kidx[k]))*64 + d] - xiL[d];
    }
    __syncthreads();
    float common = bias;
    for (int d=0; d<64; d++) common = fmaf(xiL[d], Wgf[d*C2 + c], common);
    float acc[9];
    #pragma unroll
    for (int k=0;k<9;k++) acc[k]=0.f;
    for (int d=0; d<64; d++){
      float w = Wgf[(64+d)*C2 + c];
      #pragma unroll
      for (int k=0;k<9;k++) acc[k] = fmaf(dxL[k*64+d], w, acc[k]);
    }
    #pragma unroll
    for (int k=0;k<9;k++){ float v = common + acc[k]; sm += v; ss += v*v; }
  }
  part[blockIdx.x*256 + c] = sm;
  part[blockIdx.x*256 + 128 + c] = ss;
}

// ---------------- edge conv pass 2: recompute + BN + gelu + max over K ----------
__global__ void k_edgemax(const float* __restrict__ h, const int* __restrict__ idxf,
                          const float* __restrict__ Wgf, const float* __restrict__ bg,
                          const float* __restrict__ scsh, float* __restrict__ gmax){
  __shared__ float xiL[64];
  __shared__ float dxL[9*64];
  __shared__ int kidx[9];
  int node = blockIdx.x;
  int b = node >> 12;
  int tid = threadIdx.x;
  if (tid < 64) xiL[tid] = h[(size_t)node*64 + tid];
  if (tid < 9) kidx[tid] = idxf[(size_t)node*9 + tid] & (NN-1);
  __syncthreads();
  for (int r2 = tid; r2 < 9*64; r2 += 128){
    int k = r2 >> 6; int d = r2 & 63;
    dxL[r2] = h[((size_t)(b*NN + kidx[k]))*64 + d] - xiL[d];
  }
  __syncthreads();
  int c = tid;
  float common = bg[c];
  for (int d=0; d<64; d++) common = fmaf(xiL[d], Wgf[d*C2 + c], common);
  float acc[9];
  #pragma unroll
  for (int k=0;k<9;k++) acc[k]=0.f;
  for (int d=0; d<64; d++){
    float w = Wgf[(64+d)*C2 + c];
    #pragma unroll
    for (int k=0;k<9;k++) acc[k] = fmaf(dxL[k*64+d], w, acc[k]);
  }
  float sc = scsh[c], sh = scsh[C2 + c];
  float m = -INFINITY;
  #pragma unroll
  for (int k=0;k<9;k++){
    float v = fmaf(common + acc[k], sc, sh);
    m = fmaxf(m, gelu(v));
  }
  gmax[(size_t)node*C2 + c] = m;
}

// ---------------- FFN pass 1: fused GEMM(64->256) + column stats ----------------
__global__ void k_ffn1stats(const float* __restrict__ outt, const float* __restrict__ Wf1f,
                            const float* __restrict__ bf1v, float* __restrict__ part){
  int c = threadIdx.x;
  float bias = bf1v[c];
  float sm=0.f, ss=0.f;
  for (int u=0; u<32; u++){
    int r = blockIdx.x*32 + u;
    const float* xr = outt + (size_t)r*64;
    float acc = bias;
    for (int d=0; d<64; d++) acc = fmaf(xr[d], Wf1f[d*C4 + c], acc);
    sm += acc; ss += acc*acc;
  }
  part[blockIdx.x*512 + c] = sm;
  part[blockIdx.x*512 + 256 + c] = ss;
}

// ---------------- FFN pass 2: recompute + BN + gelu + GEMM(256->64) ----------------
__global__ void k_ffn2(const float* __restrict__ outt, const float* __restrict__ Wf1f,
                       const float* __restrict__ bf1v, const float* __restrict__ scsh,
                       const float* __restrict__ Wf2f, const float* __restrict__ bf2v,
                       float* __restrict__ Yf2){
  __shared__ float xr[64];
  __shared__ float fL[256];
  __shared__ float red[256];
  int r = blockIdx.x; int tid = threadIdx.x;
  if (tid < 64) xr[tid] = outt[(size_t)r*64 + tid];
  __syncthreads();
  float acc = bf1v[tid];
  for (int d=0; d<64; d++) acc = fmaf(xr[d], Wf1f[d*C4 + tid], acc);
  float v = fmaf(acc, scsh[tid], scsh[C4 + tid]);
  fL[tid] = gelu(v);
  __syncthreads();
  int g = tid >> 6, c = tid & 63;
  float p = 0.f;
  for (int dd=0; dd<64; dd++){
    int d = g*64 + dd;
    p = fmaf(fL[d], Wf2f[d*64 + c], p);
  }
  red[tid] = p;
  __syncthreads();
  if (tid < 64){
    float y = bf2v[tid] + red[tid] + red[64+tid] + red[128+tid] + red[192+tid];
    Yf2[(size_t)r*64 + tid] = y;
  }
}

// ---------------- alpha-mix + transpose -> output (T,B,C,N) fp32 ----------------
__global__ void k_mix(const float* __restrict__ f0, const float* __restrict__ f1,
                      const float* __restrict__ alpha, float* __restrict__ outv){
  int idx = blockIdx.x*256 + threadIdx.x;
  if (idx >= TT*BB*CCH*NN) return;
  int n = idx & (NN-1);
  int c = (idx >> 12) & 63;
  int b = (idx >> 18) & 1;
  int i = idx >> 19;
  float a0 = alpha[i*TT + 0];
  float a1 = alpha[i*TT + 1];
  size_t fi = ((size_t)(b*NN + n))*64 + c;
  outv[idx] = a0*f0[fi] + a1*f1[fi];
}

extern "C" void kernel_launch(void* const* d_in, const int* in_sizes, int n_in,
                              void* d_out, int out_size, void* d_ws, size_t ws_size,
                              hipStream_t stream){
  float* outp = (float*)d_out;

  static const int expect[22] = {
    524288, 8192, 128, 128, 128, 32768, 256, 256, 256, 16384, 128, 128, 128,
    32768, 512, 512, 512, 32768, 128, 128, 128, 4
  };
  bool ok = (n_in == 22) && (out_size == TT*BB*CCH*NN) &&
            (ws_size >= WS_TOTAL*sizeof(float));
  if (ok){
    for (int i=0;i<22;i++) if (in_sizes[i] != expect[i]) { ok = false; break; }
  }
  if (!ok){
    k_zero<<<(out_size+255)/256,256,0,stream>>>(outp, out_size);
    return;
  }

  const float* x   = (const float*)d_in[0];
  const float* W1  = (const float*)d_in[1];
  const float* b1  = (const float*)d_in[2];
  const float* g1  = (const float*)d_in[3];
  const float* bt1 = (const float*)d_in[4];
  const float* Wg  = (const float*)d_in[5];
  const float* bg  = (const float*)d_in[6];
  const float* gg  = (const float*)d_in[7];
  const float* btg = (const float*)d_in[8];
  const float* W2  = (const float*)d_in[9];
  const float* b2v = (const float*)d_in[10];
  const float* g2  = (const float*)d_in[11];
  const float* bt2 = (const float*)d_in[12];
  const float* Wf1 = (const float*)d_in[13];
  const float* bf1v= (const float*)d_in[14];
  const float* gf1 = (const float*)d_in[15];
  const float* btf1= (const float*)d_in[16];
  const float* Wf2 = (const float*)d_in[17];
  const float* bf2v= (const float*)d_in[18];
  const float* gf2 = (const float*)d_in[19];
  const float* btf2= (const float*)d_in[20];
  const float* alpha=(const float*)d_in[21];
  float* ws = (float*)d_ws;

  float* x0f  = ws + 0;
  float* hbuf = ws + 524288;
  float* xnb  = ws + 1048576;
  float* sqb  = ws + 1572864;
  float* part = ws + 1581056;
  float* scsh = ws + 1712128;
  int*   idxf = (int*)(ws + 1712640);
  float* f0   = ws + 1786368;
  float* f1b  = ws + 2310656;
  float* Rbig = ws + 2834944;
  float* pdist = Rbig;
  int*   pidx  = (int*)(Rbig + (size_t)R1*SPLIT*9);
  float* gmaxb = Rbig;
  float* outt  = Rbig + 1048576;
  float* Y2    = Rbig + 1572864;
  float* Yf2   = Rbig;

  k_transpose<<<2048,256,0,stream>>>(x, x0f);
  float* feats[2] = {f0, f1b};
  for (int t=0; t<TT; t++){
    // h = BN(x0 @ W1 + b1)
    k_gemm<<<2048,256,0,stream>>>(x0f, W1 + t*CCH*CCH, b1 + t*64, hbuf, R1, 64, 64);
    k_colstats<<<64,256,0,stream>>>(hbuf, R1, 64, part);
    k_finalize<<<1,64,0,stream>>>(part, 64, 64, g1 + t*64, bt1 + t*64, (float)R1, scsh);
    k_apply<<<2048,256,0,stream>>>(hbuf, scsh, R1*64);
    // knn on normalized h
    k_rownorm<<<R1,64,0,stream>>>(hbuf, xnb, sqb);
    k_knn<<<512,256,0,stream>>>(xnb, sqb, pdist, pidx);
    k_knnmerge<<<2048,256,0,stream>>>(pdist, pidx, idxf);
    // edge conv (two-pass)
    k_edgestats<<<512,128,0,stream>>>(hbuf, idxf, Wg + t*C2*C2, bg + t*C2, part);
    k_finalize<<<1,128,0,stream>>>(part, 512, 128, gg + t*C2, btg + t*C2, (float)RG, scsh);
    k_edgemax<<<R1,128,0,stream>>>(hbuf, idxf, Wg + t*C2*C2, bg + t*C2, scsh, gmaxb);
    // out = BN(gmax @ W2 + b2) + x0
    k_gemm<<<2048,256,0,stream>>>(gmaxb, W2 + t*C2*CCH, b2v + t*64, Y2, R1, 128, 64);
    k_colstats<<<64,256,0,stream>>>(Y2, R1, 64, part);
    k_finalize<<<1,64,0,stream>>>(part, 64, 64, g2 + t*64, bt2 + t*64, (float)R1, scsh);
    k_apply_res<<<2048,256,0,stream>>>(Y2, scsh, x0f, outt, R1*64);
    // FFN (two-pass)
    k_ffn1stats<<<256,256,0,stream>>>(outt, Wf1 + t*CCH*C4, bf1v + t*C4, part);
    k_finalize<<<1,256,0,stream>>>(part, 256, 256, gf1 + t*C4, btf1 + t*C4, (float)R1, scsh);
    k_ffn2<<<R1,256,0,stream>>>(outt, Wf1 + t*CCH*C4, bf1v + t*C4, scsh, Wf2 + t*C4*CCH, bf2v + t*64, Yf2);
    k_colstats<<<64,256,0,stream>>>(Yf2, R1, 64, part);
    k_finalize<<<1,64,0,stream>>>(part, 64, 64, gf2 + t*64, btf2 + t*64, (float)R1, scsh);
    k_apply_res<<<2048,256,0,stream>>>(Yf2, scsh, outt, feats[t], R1*64);
  }
  k_mix<<<4096,256,0,stream>>>(f0, f1b, alpha, outp);
}